// Round 4
// baseline (656.835 us; speedup 1.0000x reference)
//
#include <hip/hip_runtime.h>
#include <hip/hip_bf16.h>
#include <stdint.h>

// y[b,s,o] = sum_i x[b,s,i] * (w[o,i]*mask[o,i]) + bias[o]
// Inputs fp32: x [4,2048,4096], w [4096,4096], bias [4096], mask [4096,4096].
// Output fp32 [8192,4096]. Compute: bf16 MFMA (tolerance is bf16-floor).
#define M_DIM 8192
#define N_DIM 4096
#define K_DIM 4096
#define BM 128
#define BN 128
#define BK 64            // 2x16 KB LDS tiles, 32 MFMA per barrier (halved drains)

typedef __attribute__((ext_vector_type(8))) __bf16 bf16x8;
typedef __attribute__((ext_vector_type(4))) float floatx4;

// ---------- fp32 -> bf16 (RNE) ----------
__device__ inline unsigned f2b(float f) {
    union { float f; unsigned u; } v; v.f = f;
    return (v.u + 0x7FFFu + ((v.u >> 16) & 1u)) >> 16;   // RNE; inputs finite
}
__device__ inline unsigned pk2(float lo, float hi) {
    return (f2b(lo) & 0xFFFFu) | (f2b(hi) << 16);
}
__device__ inline uint4 pk8(float4 a, float4 b) {
    uint4 o;
    o.x = pk2(a.x, a.y); o.y = pk2(a.z, a.w);
    o.z = pk2(b.x, b.y); o.w = pk2(b.z, b.w);
    return o;
}

// Async global->LDS, 16B/lane. LDS dest is wave-uniform base + lane*16
// (strictly linear); the anti-conflict swizzle is applied to the SOURCE
// address each lane fetches (same cache lines -> free).
__device__ inline void async_load16(const void* g, void* l) {
    __builtin_amdgcn_global_load_lds(
        (const __attribute__((address_space(1))) unsigned int*)(unsigned long long)g,
        (__attribute__((address_space(3))) unsigned int*)(unsigned int)(unsigned long long)l,
        16, 0, 0);
}

// ---------- Pass 1: fully-linear cvt (R2 pattern, fused into one kernel) ----
// xb = bf16(x) row-major [8192][4096]; wb = bf16(w*mask) row-major [4096][4096].
__global__ __launch_bounds__(256)
void cvt_kernel(const float* __restrict__ x, const float* __restrict__ w,
                const float* __restrict__ mask,
                uint4* __restrict__ xb, uint4* __restrict__ wb) {
    const int NX = M_DIM * K_DIM / 8;   // 4,194,304 x-chunks
    int tid = blockIdx.x * 256 + threadIdx.x;
    if (tid < NX) {
        const float4* s = (const float4*)(x + (size_t)tid * 8);
        xb[tid] = pk8(s[0], s[1]);
    } else {
        int j = tid - NX;               // < 2,097,152
        const float4* ws_ = (const float4*)(w + (size_t)j * 8);
        const float4* ms  = (const float4*)(mask + (size_t)j * 8);
        float4 a = ws_[0], b = ws_[1], qa = ms[0], qb = ms[1];
        a.x *= qa.x; a.y *= qa.y; a.z *= qa.z; a.w *= qa.w;
        b.x *= qb.x; b.y *= qb.y; b.z *= qb.z; b.w *= qb.w;
        wb[j] = pk8(a, b);
    }
}

// ---------- Pass 2: C = A @ B^T + bias, BK=64, swizzle-at-DMA-source -------
// LDS image: 16B chunk (r4, ksub) of the 128x64 tile sits at slot
// r4*8 + (ksub ^ (r4&7)).  Staging thread with linear chunk id c fetches
// source ksub = (c&7) ^ ((c>>3)&7).  Fragment read column for k-half h,
// quad q, row lm:  (h*4+q) ^ (lm&7)  -> 8 distinct columns per 16-lane
// phase group = 2-way bank aliasing = free (m136).
__global__ __launch_bounds__(256)
void gemm_bt_bias(const __hip_bfloat16* __restrict__ A,
                  const __hip_bfloat16* __restrict__ B,
                  const float* __restrict__ bias,
                  float* __restrict__ C) {
    __shared__ __align__(16) __hip_bfloat16 As[BM * BK];   // 16 KB
    __shared__ __align__(16) __hip_bfloat16 Bs[BN * BK];   // 16 KB

    const int t    = threadIdx.x;
    const int lane = t & 63;
    const int wave = t >> 6;
    const int wm   = wave >> 1;
    const int wn   = wave & 1;
    const int m0   = blockIdx.y * BM;
    const int n0   = blockIdx.x * BN;
    const int lm   = lane & 15;
    const int q    = lane >> 4;

    // Per-thread staging source offsets (elements within tile, k0 added later)
    int offS[4];
#pragma unroll
    for (int u = 0; u < 4; u++) {
        const int c  = t + 256 * u;
        const int r4 = c >> 3;
        const int ks = (c & 7) ^ (r4 & 7);
        offS[u] = r4 * K_DIM + ks * 8;
    }

    const __hip_bfloat16* Ab = A + (size_t)m0 * K_DIM;
    const __hip_bfloat16* Bb = B + (size_t)n0 * K_DIM;

    const int colb = q ^ (lm & 7);
    const __hip_bfloat16* aF0 = As + (wm * 64 + lm) * 64 + colb * 8;
    const __hip_bfloat16* aF1 = As + (wm * 64 + lm) * 64 + (colb ^ 4) * 8;
    const __hip_bfloat16* bF0 = Bs + (wn * 64 + lm) * 64 + colb * 8;
    const __hip_bfloat16* bF1 = Bs + (wn * 64 + lm) * 64 + (colb ^ 4) * 8;

    floatx4 acc[4][4] = {};

    for (int k0 = 0; k0 < K_DIM; k0 += BK) {
#pragma unroll
        for (int u = 0; u < 4; u++)
            async_load16(Ab + k0 + offS[u], As + (t + 256 * u) * 8);
#pragma unroll
        for (int u = 0; u < 4; u++)
            async_load16(Bb + k0 + offS[u], Bs + (t + 256 * u) * 8);
        __syncthreads();   // drains vmcnt -> staged tiles visible

        {   // k-half 0
            bf16x8 af[4], bfr[4];
#pragma unroll
            for (int i = 0; i < 4; i++) af[i]  = *(const bf16x8*)(aF0 + i * 1024);
#pragma unroll
            for (int j = 0; j < 4; j++) bfr[j] = *(const bf16x8*)(bF0 + j * 1024);
#pragma unroll
            for (int i = 0; i < 4; i++)
#pragma unroll
                for (int j = 0; j < 4; j++)
                    acc[i][j] = __builtin_amdgcn_mfma_f32_16x16x32_bf16(
                        af[i], bfr[j], acc[i][j], 0, 0, 0);
        }
        {   // k-half 1
            bf16x8 af[4], bfr[4];
#pragma unroll
            for (int i = 0; i < 4; i++) af[i]  = *(const bf16x8*)(aF1 + i * 1024);
#pragma unroll
            for (int j = 0; j < 4; j++) bfr[j] = *(const bf16x8*)(bF1 + j * 1024);
#pragma unroll
            for (int i = 0; i < 4; i++)
#pragma unroll
                for (int j = 0; j < 4; j++)
                    acc[i][j] = __builtin_amdgcn_mfma_f32_16x16x32_bf16(
                        af[i], bfr[j], acc[i][j], 0, 0, 0);
        }
        __syncthreads();
    }

    // Epilogue. C/D layout: col = lane&15, row = (lane>>4)*4 + reg.
    float bv[4];
#pragma unroll
    for (int j = 0; j < 4; j++)
        bv[j] = bias[n0 + wn * 64 + j * 16 + lm];
    const int row_base = m0 + wm * 64 + q * 4;
    const int col_base = n0 + wn * 64 + lm;
#pragma unroll
    for (int i = 0; i < 4; i++)
#pragma unroll
        for (int j = 0; j < 4; j++) {
            const int col = col_base + j * 16;
#pragma unroll
            for (int r = 0; r < 4; r++)
                C[(size_t)(row_base + i * 16 + r) * N_DIM + col] =
                    acc[i][j][r] + bv[j];
        }
}

// ---------- Fallback (ws too small): fuse cvt+mask into staging, BK=32 -----
#define FBK 32
__global__ __launch_bounds__(256)
void gemm_fused_f32(const float* __restrict__ A, const float* __restrict__ W,
                    const float* __restrict__ Mk, const float* __restrict__ bias,
                    float* __restrict__ C) {
    __shared__ __hip_bfloat16 As[BM * FBK];
    __shared__ __hip_bfloat16 Bs[BN * FBK];
    const int t = threadIdx.x, lane = t & 63, wave = t >> 6;
    const int wm = wave >> 1, wn = wave & 1;
    const int m0 = blockIdx.y * BM, n0 = blockIdx.x * BN;
    const int lm = lane & 15, lk = (lane >> 4) << 3;
    floatx4 acc[4][4] = {};
    const int r = t >> 1, cb = (t & 1) * 16;
    for (int k0 = 0; k0 < K_DIM; k0 += FBK) {
        const float* ap = A + (size_t)(m0 + r) * K_DIM + k0 + cb;
        float4 f0 = ((const float4*)ap)[0], f1 = ((const float4*)ap)[1];
        float4 f2 = ((const float4*)ap)[2], f3 = ((const float4*)ap)[3];
        *(uint4*)&As[r * FBK + cb] = pk8(f0, f1);
        *(uint4*)&As[r * FBK + cb + 8] = pk8(f2, f3);
        const float* wp = W + (size_t)(n0 + r) * K_DIM + k0 + cb;
        const float* mp = Mk + (size_t)(n0 + r) * K_DIM + k0 + cb;
        float4 w0 = ((const float4*)wp)[0], w1 = ((const float4*)wp)[1];
        float4 w2 = ((const float4*)wp)[2], w3 = ((const float4*)wp)[3];
        float4 q0 = ((const float4*)mp)[0], q1 = ((const float4*)mp)[1];
        float4 q2 = ((const float4*)mp)[2], q3 = ((const float4*)mp)[3];
        w0.x*=q0.x; w0.y*=q0.y; w0.z*=q0.z; w0.w*=q0.w;
        w1.x*=q1.x; w1.y*=q1.y; w1.z*=q1.z; w1.w*=q1.w;
        w2.x*=q2.x; w2.y*=q2.y; w2.z*=q2.z; w2.w*=q2.w;
        w3.x*=q3.x; w3.y*=q3.y; w3.z*=q3.z; w3.w*=q3.w;
        *(uint4*)&Bs[r * FBK + cb] = pk8(w0, w1);
        *(uint4*)&Bs[r * FBK + cb + 8] = pk8(w2, w3);
        __syncthreads();
        bf16x8 af[4], bfr[4];
#pragma unroll
        for (int i = 0; i < 4; i++)
            af[i] = *(const bf16x8*)(&As[(wm * 64 + i * 16 + lm) * FBK + lk]);
#pragma unroll
        for (int j = 0; j < 4; j++)
            bfr[j] = *(const bf16x8*)(&Bs[(wn * 64 + j * 16 + lm) * FBK + lk]);
#pragma unroll
        for (int i = 0; i < 4; i++)
#pragma unroll
            for (int j = 0; j < 4; j++)
                acc[i][j] = __builtin_amdgcn_mfma_f32_16x16x32_bf16(
                    af[i], bfr[j], acc[i][j], 0, 0, 0);
        __syncthreads();
    }
    float bv[4];
#pragma unroll
    for (int j = 0; j < 4; j++) bv[j] = bias[n0 + wn * 64 + j * 16 + lm];
    const int row_base = m0 + wm * 64 + (lane >> 4) * 4;
    const int col_base = n0 + wn * 64 + lm;
#pragma unroll
    for (int i = 0; i < 4; i++)
#pragma unroll
        for (int j = 0; j < 4; j++) {
            const int col = col_base + j * 16;
#pragma unroll
            for (int r4 = 0; r4 < 4; r4++)
                C[(size_t)(row_base + i * 16 + r4) * N_DIM + col] =
                    acc[i][j][r4] + bv[j];
        }
}

extern "C" void kernel_launch(void* const* d_in, const int* in_sizes, int n_in,
                              void* d_out, int out_size, void* d_ws, size_t ws_size,
                              hipStream_t stream) {
    const float* x    = (const float*)d_in[0];
    const float* w    = (const float*)d_in[1];
    const float* bias = (const float*)d_in[2];
    const float* mask = (const float*)d_in[3];
    float* out = (float*)d_out;

    const size_t xb_bytes = (size_t)M_DIM * K_DIM * 2;   // 64 MiB
    const size_t wb_bytes = (size_t)N_DIM * K_DIM * 2;   // 32 MiB
    dim3 grid(N_DIM / BN, M_DIM / BM);   // 32 x 64
    dim3 block(256);

    if (ws_size >= xb_bytes + wb_bytes) {
        uint4* xb = (uint4*)d_ws;
        uint4* wb = (uint4*)((char*)d_ws + xb_bytes);
        const int nchunks = (M_DIM * K_DIM + N_DIM * K_DIM) / 8;  // 6,291,456
        cvt_kernel<<<dim3(nchunks / 256), block, 0, stream>>>(x, w, mask, xb, wb);
        gemm_bt_bias<<<grid, block, 0, stream>>>(
            (const __hip_bfloat16*)xb, (const __hip_bfloat16*)wb, bias, out);
    } else {
        gemm_fused_f32<<<grid, block, 0, stream>>>(x, w, mask, bias, out);
    }
}